// Round 6
// baseline (258.094 us; speedup 1.0000x reference)
//
#include <hip/hip_runtime.h>
#include <stdint.h>

// LoRA linear, SPLIT structure (counter-verified rounds 1-5):
//   phase1: t = 2 * (x @ A^T)     [8192,16]   -- read-stream x (134 MB)
//   phase2: out = t @ B^T + bias  [8192,4096] -- write-stream out (134 MB)
//
// ROUND-5 LESSON: phase1 is no longer bytes-bound (201 MB total vmem ~14 us
// at the measured per-CU L1 rate) -- it is BARRIER-DRAIN bound:
// __syncthreads = s_waitcnt vmcnt(0) + s_barrier, which drains the
// JUST-ISSUED next-chunk prefetch (2 gl_lds + 4 x) every iteration,
// collapsing the 1-iteration prefetch distance to zero. With 1 block/CU
// there is nothing else to cover the ~3000-cyc per-iter HBM burst.
//
// THIS ROUND (T3/T4): counted vmcnt + raw s_barrier double-buffer:
//   iter j: issue stage(j+1)+x(j+1)  -> s_waitcnt vmcnt(6)  [drains only
//   loads issued >= 1 iter ago, i.e. exactly what iter j consumes]
//   -> s_barrier -> compute -> s_barrier [protects buffer (j&1) from
//   being overwritten by stage(j+2) before all waves finished reading].
// Last iter: vmcnt(0) (nothing newer in flight). x/A now stream
// continuously instead of burst-drain-stall.
// Phase2: 32 rows/block (BT traffic 67->34 MB; stores already coalesced).

constexpr int IN_F  = 4096;
constexpr int OUT_F = 4096;
constexpr int RANK  = 16;
constexpr int M_TOT = 8192;               // token rows
constexpr float SCALING = 2.0f;           // ALPHA / R

typedef const __attribute__((address_space(1))) void* as1_cvp;
typedef __attribute__((address_space(3))) void*       as3_vp;
typedef float f32x4 __attribute__((ext_vector_type(4)));

// ---------------- Kernel 1: t = 2 * (x @ A^T)  (+ B transpose tail) --------
// block = 512 (8 waves); wave handles 4 rows -> 32 rows/block; grid 256
// (1 block/CU). Per j-chunk (256 cols): 16 KB A-chunk staged ONCE per block
// (wave w stages ranks 2w, 2w+1 via global_load_lds width=16, dst =
// base + lane*16 = consume layout), double-buffered with counted vmcnt.
__global__ __launch_bounds__(512, 2) void lora_phase1(
    const float* __restrict__ x, const float* __restrict__ A,
    const float* __restrict__ B, float* __restrict__ t,
    float* __restrict__ BT)
{
    __shared__ float4 As[2][RANK][64];    // 2 x 16 KB
    const int lane = threadIdx.x & 63;
    const int wave = threadIdx.x >> 6;    // 0..7
    const int row0 = blockIdx.x * 32 + wave * 4;

    const float4* __restrict__ A4 = (const float4*)A;
    const float4* __restrict__ x0 = (const float4*)(x + (size_t)(row0 + 0) * IN_F);
    const float4* __restrict__ x1 = (const float4*)(x + (size_t)(row0 + 1) * IN_F);
    const float4* __restrict__ x2 = (const float4*)(x + (size_t)(row0 + 2) * IN_F);
    const float4* __restrict__ x3 = (const float4*)(x + (size_t)(row0 + 3) * IN_F);

    float acc0[RANK], acc1[RANK], acc2[RANK], acc3[RANK];
#pragma unroll
    for (int r = 0; r < RANK; ++r) {
        acc0[r] = 0.0f; acc1[r] = 0.0f; acc2[r] = 0.0f; acc3[r] = 0.0f;
    }

    // Prologue: issue stage(0) -> buf 0 and x(0). 6 vmem ops outstanding,
    // matching the steady-state invariant at the in-loop wait.
#pragma unroll
    for (int rr = 0; rr < 2; ++rr) {
        const int r = wave * 2 + rr;
        __builtin_amdgcn_global_load_lds((as1_cvp)(A4 + (size_t)r * (IN_F / 4) + lane),
                                         (as3_vp)(&As[0][r][0]), 16, 0, 0);
    }
    float4 xc0 = x0[lane];
    float4 xc1 = x1[lane];
    float4 xc2 = x2[lane];
    float4 xc3 = x3[lane];

#pragma unroll 1
    for (int j = 0; j < 16; ++j) {
        const int buf = j & 1;
        float4 xn0, xn1, xn2, xn3;
        if (j < 15) {
            // Issue next-chunk prefetch: 2 gl_lds into buf^1 + 4 x loads.
            const int c4 = (j + 1) * 64 + lane;
#pragma unroll
            for (int rr = 0; rr < 2; ++rr) {
                const int r = wave * 2 + rr;
                __builtin_amdgcn_global_load_lds(
                    (as1_cvp)(A4 + (size_t)r * (IN_F / 4) + c4),
                    (as3_vp)(&As[buf ^ 1][r][0]), 16, 0, 0);
            }
            xn0 = x0[c4];
            xn1 = x1[c4];
            xn2 = x2[c4];
            xn3 = x3[c4];
            // Counted wait: the 6 newest (just issued) may remain in flight;
            // everything older -- stage(j) and x(j), issued a full iteration
            // ago -- is guaranteed complete.
            asm volatile("s_waitcnt vmcnt(6)" ::: "memory");
        } else {
            // Final iteration: drain the last stage/x (they ARE the newest).
            asm volatile("s_waitcnt vmcnt(0)" ::: "memory");
        }
        __builtin_amdgcn_s_barrier();   // all waves' stage(j) landed

#pragma unroll
        for (int r = 0; r < RANK; ++r) {
            const float4 av = As[buf][r][lane];   // ds_read_b128, conflict-free
            acc0[r] += xc0.x * av.x; acc0[r] += xc0.y * av.y;
            acc0[r] += xc0.z * av.z; acc0[r] += xc0.w * av.w;
            acc1[r] += xc1.x * av.x; acc1[r] += xc1.y * av.y;
            acc1[r] += xc1.z * av.z; acc1[r] += xc1.w * av.w;
            acc2[r] += xc2.x * av.x; acc2[r] += xc2.y * av.y;
            acc2[r] += xc2.z * av.z; acc2[r] += xc2.w * av.w;
            acc3[r] += xc3.x * av.x; acc3[r] += xc3.y * av.y;
            acc3[r] += xc3.z * av.z; acc3[r] += xc3.w * av.w;
        }

        if (j < 15) {
            // Protect As[buf] from stage(j+2) (which writes buf) until all
            // waves finished reading it. lgkmcnt waits for the ds_reads are
            // compiler-inserted before the FMA uses above.
            __builtin_amdgcn_s_barrier();
            xc0 = xn0; xc1 = xn1; xc2 = xn2; xc3 = xn3;
        }
    }

    // Cross-lane butterfly reduce (64 lanes) for each of the 4x16 sums.
#pragma unroll
    for (int p = 0; p < 4; ++p) {
        float out_v = 0.0f;
#pragma unroll
        for (int r = 0; r < RANK; ++r) {
            float v = (p == 0) ? acc0[r] : (p == 1) ? acc1[r]
                    : (p == 2) ? acc2[r] : acc3[r];
#pragma unroll
            for (int s = 1; s < 64; s <<= 1)
                v += __shfl_xor(v, s, 64);
            out_v = (lane == r) ? v : out_v;
        }
        if (lane < RANK)
            t[(size_t)(row0 + p) * RANK + lane] = SCALING * out_v;
    }

    // ---- B transpose tail (blocks 0..31): BT[r][o] = B[o][r], 256 KB ----
    if (BT != nullptr && blockIdx.x < 32) {
        const int id = blockIdx.x * 512 + threadIdx.x;   // 0..16383
        const int r  = id >> 10;                         // 0..15
        const int c4 = id & 1023;                        // float4-col in BT row
        f32x4 v;
        v.x = B[(size_t)(4 * c4 + 0) * RANK + r];
        v.y = B[(size_t)(4 * c4 + 1) * RANK + r];
        v.z = B[(size_t)(4 * c4 + 2) * RANK + r];
        v.w = B[(size_t)(4 * c4 + 3) * RANK + r];
        ((f32x4*)BT)[(size_t)r * (OUT_F / 4) + c4] = v;
    }
}

// ---------------- Kernel 2 (BT path): out = t @ B^T + bias ----------------
// block = 256; thread owns 4 cols x 32 rows; grid (4, 256) = 1024 blocks.
// b[16] (lane-contiguous float4 loads from BT) amortized over 32 rows.
__global__ __launch_bounds__(256) void lora_phase2t(
    const float* __restrict__ t, const float* __restrict__ BT,
    const float* __restrict__ bias, float* __restrict__ out)
{
    const int o0 = blockIdx.x * 1024 + threadIdx.x * 4;  // first owned column
    const int m0 = blockIdx.y * 32;                      // first row

    const f32x4* __restrict__ BT4 = (const f32x4*)BT;
    const float4* __restrict__ t4 = (const float4*)t;

    // b[r] = BT[r][o0..o0+3] -- lanes contiguous, coalesced (1 KB/instr)
    f32x4 b[16];
#pragma unroll
    for (int r = 0; r < 16; ++r)
        b[r] = BT4[(size_t)r * (OUT_F / 4) + (o0 >> 2)];

    const f32x4 bs = *(const f32x4*)(bias + o0);

#pragma unroll
    for (int mi = 0; mi < 32; ++mi) {
        // t row (uniform across block -> scalar s_load path, L2-resident)
        const float4 tv0 = t4[(size_t)(m0 + mi) * 4 + 0];
        const float4 tv1 = t4[(size_t)(m0 + mi) * 4 + 1];
        const float4 tv2 = t4[(size_t)(m0 + mi) * 4 + 2];
        const float4 tv3 = t4[(size_t)(m0 + mi) * 4 + 3];

        f32x4 v = bs;
        v += b[0]  * tv0.x; v += b[1]  * tv0.y; v += b[2]  * tv0.z; v += b[3]  * tv0.w;
        v += b[4]  * tv1.x; v += b[5]  * tv1.y; v += b[6]  * tv1.z; v += b[7]  * tv1.w;
        v += b[8]  * tv2.x; v += b[9]  * tv2.y; v += b[10] * tv2.z; v += b[11] * tv2.w;
        v += b[12] * tv3.x; v += b[13] * tv3.y; v += b[14] * tv3.z; v += b[15] * tv3.w;

        *(f32x4*)(out + (size_t)(m0 + mi) * OUT_F + o0) = v;
    }
}

// ---------------- Kernel 2 (fallback, ws too small): old strided-B ----------
__global__ __launch_bounds__(256) void lora_phase2(
    const float* __restrict__ t, const float* __restrict__ B,
    const float* __restrict__ bias, float* __restrict__ out)
{
    const int o0 = blockIdx.x * 1024 + threadIdx.x * 4;
    const int m0 = blockIdx.y * 4;

    const float4* __restrict__ B4 = (const float4*)B;
    const float4* __restrict__ t4 = (const float4*)t;

    float4 b[4][4];
#pragma unroll
    for (int q = 0; q < 4; ++q)
#pragma unroll
        for (int rr = 0; rr < 4; ++rr)
            b[q][rr] = B4[(size_t)(o0 + q) * 4 + rr];

    float4 tv[4][4];
#pragma unroll
    for (int mi = 0; mi < 4; ++mi)
#pragma unroll
        for (int rr = 0; rr < 4; ++rr)
            tv[mi][rr] = t4[(size_t)(m0 + mi) * 4 + rr];

    const float4 bs = *(const float4*)(bias + o0);

#pragma unroll
    for (int mi = 0; mi < 4; ++mi) {
        float v[4] = {bs.x, bs.y, bs.z, bs.w};
#pragma unroll
        for (int q = 0; q < 4; ++q) {
#pragma unroll
            for (int rr = 0; rr < 4; ++rr) {
                v[q] += b[q][rr].x * tv[mi][rr].x;
                v[q] += b[q][rr].y * tv[mi][rr].y;
                v[q] += b[q][rr].z * tv[mi][rr].z;
                v[q] += b[q][rr].w * tv[mi][rr].w;
            }
        }
        float4 o4 = {v[0], v[1], v[2], v[3]};
        *(float4*)(out + (size_t)(m0 + mi) * OUT_F + o0) = o4;
    }
}

extern "C" void kernel_launch(void* const* d_in, const int* in_sizes, int n_in,
                              void* d_out, int out_size, void* d_ws, size_t ws_size,
                              hipStream_t stream) {
    const float* x    = (const float*)d_in[0];  // [8192, 4096]
    const float* A    = (const float*)d_in[1];  // [16, 4096]
    const float* B    = (const float*)d_in[2];  // [4096, 16]
    const float* bias = (const float*)d_in[3];  // [4096]
    float* out = (float*)d_out;                 // [8192, 4096]
    float* t   = (float*)d_ws;                  // [8192, 16] scratch (512 KB)

    const size_t need_bt = (size_t)(M_TOT * RANK + RANK * OUT_F) * sizeof(float);
    const bool use_bt = ws_size >= need_bt;     // 768 KB
    float* BT = t + (size_t)M_TOT * RANK;       // [16, 4096] (256 KB)

    // Phase 1: t = 2 * x @ A^T  (32 rows/block; counted-vmcnt pipeline;
    // B-transpose tail in blocks 0..31)
    lora_phase1<<<dim3(M_TOT / 32), dim3(512), 0, stream>>>(
        x, A, B, t, use_bt ? BT : nullptr);

    // Phase 2: out = t @ B^T + bias
    if (use_bt)
        lora_phase2t<<<dim3(OUT_F / 1024, M_TOT / 32), dim3(256), 0, stream>>>(t, BT, bias, out);
    else
        lora_phase2<<<dim3(OUT_F / 1024, M_TOT / 4), dim3(256), 0, stream>>>(t, B, bias, out);
}